// Round 1
// baseline (137.597 us; speedup 1.0000x reference)
//
#include <hip/hip_runtime.h>
#include <hip/hip_bf16.h>

// SNNDecode: z = x @ W^T  (einsum 'bsh,oh->sbo'), then linear LI scan over seq.
//   v_t = v_{t-1} + a*(i_{t-1} - v_{t-1});  i_t = (1-b)*i_{t-1} + z_t;  out[t]=v_t
//   a = DT*clamp(tau_mem), b = DT*clamp(tau_syn)
// d_out = [voltages (2048*64*128)] ++ [v_f (8192)] ++ [i_f (8192)]  (fp32)
// Workspace use: 2 MiB (chunk end/in states). Assumes ws_size >= 2 MiB.

typedef __attribute__((ext_vector_type(4))) float f4;
typedef __attribute__((ext_vector_type(8))) short s8;

#define SEQ    2048
#define HID    512
#define CHAINS 8192          // batch(64) * out(128)
#define VOLT   16777216      // SEQ * CHAINS
#define CHUNK  64
#define NCH    32            // SEQ / CHUNK

__device__ __forceinline__ float clamp01(float x) { return fminf(fmaxf(x, 0.f), 1.f); }

// fp32 -> bf16 bits, round-to-nearest-even
__device__ __forceinline__ short f2bf(float f) {
  union { float f; unsigned u; } c; c.f = f;
  unsigned u = c.u;
  unsigned r = (u + 0x7fffu + ((u >> 16) & 1u)) >> 16;
  return (short)r;
}

// LDS swizzle (ushort-index units): XOR row-low-bits into k bits 3..5 so that
// both ds_write_b128 staging and ds_read_b128 fragment reads load all 32 banks
// evenly (8 requests/bank over the 8-cycle minimum of a wave64 b128 access).
__device__ __forceinline__ int swz(int row, int k) {
  return (row * 64 + k) ^ ((row & 7) << 3);
}

// ---------------- Phase 1: z[(t*64+b)*128+o] = sum_h x[b][t][h]*W[o][h] -----
// 128x128 tile, BK=64, 4 waves (2x2), mfma_f32_16x16x32_bf16, fp32->bf16 on the fly.
__global__ __launch_bounds__(256, 2) void k_gemm(const float* __restrict__ X,
                                                 const float* __restrict__ W,
                                                 float* __restrict__ Z) {
  __shared__ short As[128 * 64];
  __shared__ short Bs[128 * 64];
  const int tid = threadIdx.x;
  const int m0  = blockIdx.x << 7;   // global row = b*2048 + t
  const int b   = m0 >> 11;          // constant per block (128 | 2048)
  const int t0  = m0 & 2047;

  const int rbase = tid >> 3;        // 0..31: staging row group
  const int coff  = (tid & 7) << 3;  // 0..56: staging k offset (8 floats)

  const int lane = tid & 63;
  const int wid  = tid >> 6;
  const int wmb  = (wid >> 1) << 6;  // wave row base: 0/64
  const int wnb  = (wid & 1) << 6;   // wave col base: 0/64
  const int lr   = lane & 15;
  const int lk   = (lane >> 4) << 3;

  f4 acc[4][4];
#pragma unroll
  for (int mi = 0; mi < 4; ++mi)
#pragma unroll
    for (int ni = 0; ni < 4; ++ni) acc[mi][ni] = (f4){0.f, 0.f, 0.f, 0.f};

  for (int ks = 0; ks < 8; ++ks) {
    const int k0 = ks << 6;
    // Issue global loads (256B-contiguous per 8-lane group) before the barrier
    // so HBM latency overlaps the other waves' previous MFMA + barrier wait.
    f4 xa[4][2], wb[4][2];
#pragma unroll
    for (int c = 0; c < 4; ++c) {
      const int row = (c << 5) + rbase;
      const float* px = X + (size_t)(m0 + row) * HID + k0 + coff;
      const float* pw = W + (size_t)row * HID + k0 + coff;
      xa[c][0] = *(const f4*)px;  xa[c][1] = *(const f4*)(px + 4);
      wb[c][0] = *(const f4*)pw;  wb[c][1] = *(const f4*)(pw + 4);
    }
    __syncthreads();  // previous iteration's ds_reads done
#pragma unroll
    for (int c = 0; c < 4; ++c) {
      const int row = (c << 5) + rbase;
      s8 va, vb;
#pragma unroll
      for (int j = 0; j < 4; ++j) {
        va[j] = f2bf(xa[c][0][j]); va[j + 4] = f2bf(xa[c][1][j]);
        vb[j] = f2bf(wb[c][0][j]); vb[j + 4] = f2bf(wb[c][1][j]);
      }
      *(s8*)&As[swz(row, coff)] = va;
      *(s8*)&Bs[swz(row, coff)] = vb;
    }
    __syncthreads();
#pragma unroll
    for (int kk = 0; kk < 2; ++kk) {
      s8 af[4], bg[4];
#pragma unroll
      for (int mi = 0; mi < 4; ++mi)
        af[mi] = *(const s8*)&As[swz(wmb + (mi << 4) + lr, (kk << 5) + lk)];
#pragma unroll
      for (int ni = 0; ni < 4; ++ni)
        bg[ni] = *(const s8*)&Bs[swz(wnb + (ni << 4) + lr, (kk << 5) + lk)];
#pragma unroll
      for (int mi = 0; mi < 4; ++mi)
#pragma unroll
        for (int ni = 0; ni < 4; ++ni)
          acc[mi][ni] = __builtin_amdgcn_mfma_f32_16x16x32_bf16(af[mi], bg[ni],
                                                                acc[mi][ni], 0, 0, 0);
    }
  }
  // Epilogue: C/D layout col=lane&15, row=(lane>>4)*4+reg (m89-verified).
  const int rr = (lane >> 4) << 2;
#pragma unroll
  for (int mi = 0; mi < 4; ++mi) {
    const int trow = t0 + wmb + (mi << 4) + rr;
#pragma unroll
    for (int ni = 0; ni < 4; ++ni) {
      const int col = wnb + (ni << 4) + lr;
#pragma unroll
      for (int r = 0; r < 4; ++r)
        Z[(size_t)(trow + r) * 8192 + (b << 7) + col] = acc[mi][ni][r];
    }
  }
}

// ---------------- Phase 2a: per-chunk scan from zero state, record end states.
// Thread = (chain-group of 4, chunk). Lanes 0..63 = 64 consecutive chain-groups
// -> every wave load is 1KB contiguous.
__global__ __launch_bounds__(256) void k_states(const float* __restrict__ tau_syn,
                                                const float* __restrict__ tau_mem,
                                                const float* __restrict__ Z,
                                                float* __restrict__ ws) {
  const int tid = threadIdx.x;
  const int cg = (blockIdx.x & 31) * 64 + (tid & 63);  // 0..2047
  const int q  = (blockIdx.x >> 5) * 4 + (tid >> 6);   // 0..31
  const float a  = 0.001f * clamp01(tau_mem[0]);
  const float bb = 0.001f * clamp01(tau_syn[0]);
  const float eb = 1.f - bb;
  const f4* z4 = (const f4*)Z;
  f4 v = (f4){0.f, 0.f, 0.f, 0.f}, ii = (f4){0.f, 0.f, 0.f, 0.f};
  const int tb = q << 6;
#pragma unroll 8
  for (int j = 0; j < CHUNK; ++j) {
    f4 z = z4[(size_t)(tb + j) * 2048 + cg];
    v  = v + a * (ii - v);
    ii = eb * ii + z;
  }
  f4* vend = (f4*)ws;          // [NCH][2048] f4
  f4* iend = vend + NCH * 2048;
  vend[q * 2048 + cg] = v;
  iend[q * 2048 + cg] = ii;
}

// ---------------- Phase 2b: combine chunk states along time; emit finals.
// s_out = M^L s_in + s_local_end;  M^L first row = [P,Q], [M^L]_11 = R.
__global__ __launch_bounds__(256) void k_combine(const float* __restrict__ tau_syn,
                                                 const float* __restrict__ tau_mem,
                                                 float* __restrict__ Out,
                                                 float* __restrict__ ws) {
  const int c = blockIdx.x * 256 + threadIdx.x;  // chain 0..8191
  const float a  = 0.001f * clamp01(tau_mem[0]);
  const float bb = 0.001f * clamp01(tau_syn[0]);
  const float ea = 1.f - a, eb = 1.f - bb;
  float P = 1.f, Q = 0.f, R = 1.f;
#pragma unroll
  for (int j = 0; j < CHUNK; ++j) { float Pn = P * ea; Q = P * a + Q * eb; P = Pn; R *= eb; }
  float* vend = ws;
  float* iend = ws + NCH * CHAINS;
  float sv = 0.f, si = 0.f;
  for (int q = 0; q < NCH; ++q) {
    const int idx = q * CHAINS + c;
    const float ve = vend[idx], ie = iend[idx];
    vend[idx] = sv;  iend[idx] = si;   // overwrite with in-states (in-place)
    const float nv = P * sv + Q * si + ve;
    si = R * si + ie;
    sv = nv;
  }
  Out[VOLT + c] = sv;            // v_f
  Out[VOLT + CHAINS + c] = si;   // i_f
}

// ---------------- Phase 2c: exact per-chunk re-scan from true in-state;
// writes v over z in place (each (t,chain) owned by exactly one thread).
__global__ __launch_bounds__(256) void k_emit(const float* __restrict__ tau_syn,
                                              const float* __restrict__ tau_mem,
                                              float* Z,
                                              const float* __restrict__ ws) {
  const int tid = threadIdx.x;
  const int cg = (blockIdx.x & 31) * 64 + (tid & 63);
  const int q  = (blockIdx.x >> 5) * 4 + (tid >> 6);
  const float a  = 0.001f * clamp01(tau_mem[0]);
  const float bb = 0.001f * clamp01(tau_syn[0]);
  const float eb = 1.f - bb;
  f4* z4 = (f4*)Z;
  const f4* vin = (const f4*)ws;
  const f4* iin = vin + NCH * 2048;
  f4 v  = vin[q * 2048 + cg];
  f4 ii = iin[q * 2048 + cg];
  const int tb = q << 6;
#pragma unroll 8
  for (int j = 0; j < CHUNK; ++j) {
    const size_t idx = (size_t)(tb + j) * 2048 + cg;
    f4 z = z4[idx];
    v  = v + a * (ii - v);
    z4[idx] = v;
    ii = eb * ii + z;
  }
}

extern "C" void kernel_launch(void* const* d_in, const int* in_sizes, int n_in,
                              void* d_out, int out_size, void* d_ws, size_t ws_size,
                              hipStream_t stream) {
  const float* X   = (const float*)d_in[0];  // [64][2048][512]
  const float* W   = (const float*)d_in[1];  // [128][512]
  const float* tsy = (const float*)d_in[2];
  const float* tme = (const float*)d_in[3];
  float* Out = (float*)d_out;
  float* ws  = (float*)d_ws;   // needs 2 MiB

  k_gemm<<<1024, 256, 0, stream>>>(X, W, Out);          // z -> voltages region
  k_states<<<256, 256, 0, stream>>>(tsy, tme, Out, ws); // chunk end states
  k_combine<<<32, 256, 0, stream>>>(tsy, tme, Out, ws); // in-states + v_f/i_f
  k_emit<<<256, 256, 0, stream>>>(tsy, tme, Out, ws);   // v over z, in place
}